// Round 1
// baseline (31.102 us; speedup 1.0000x reference)
//
#include <hip/hip_runtime.h>

// PillarFeatureNet fused: decorate(9) -> linear(64) -> BN(eval) -> relu -> max over points
// 1 wave = 1 pillar, lane = output unit.

#define NPIL   40000
#define PPTS   32
#define NUNITS 64
#define NBLK   2048
#define WPB    4        // waves per block
#define BLOCK  (WPB * 64)

__global__ __launch_bounds__(BLOCK, 8)
void pfn_fused_kernel(const float* __restrict__ features,   // [N,32,4]
                      const int*   __restrict__ num_voxels, // [N]
                      const int*   __restrict__ coors,      // [N,4]
                      const float* __restrict__ Wm,         // [64,9]
                      const float* __restrict__ gamma,      // [64]
                      const float* __restrict__ beta,       // [64]
                      const float* __restrict__ rmean,      // [64]
                      const float* __restrict__ rvar,       // [64]
                      float* __restrict__ out)              // [N,64]
{
    __shared__ float lds[WPB][PPTS * 4];

    const int lane = threadIdx.x & 63;
    const int wid  = threadIdx.x >> 6;

    // ---- per-thread (= per output unit) constants, amortized over grid-stride loop ----
    const float w0 = Wm[lane * 9 + 0], w1 = Wm[lane * 9 + 1], w2 = Wm[lane * 9 + 2];
    const float w3 = Wm[lane * 9 + 3], w4 = Wm[lane * 9 + 4], w5 = Wm[lane * 9 + 5];
    const float w6 = Wm[lane * 9 + 6], w7 = Wm[lane * 9 + 7], w8 = Wm[lane * 9 + 8];
    const float s  = gamma[lane] * rsqrtf(rvar[lane] + 1e-3f);
    const float tb = beta[lane] - rmean[lane] * s;           // BN bias term
    // BN scale folded into linear coefficients:
    const float A0 = (w0 + w4 + w7) * s;
    const float A1 = (w1 + w5 + w8) * s;
    const float A2 = (w2 + w6) * s;
    const float A3 = w3 * s;
    const float W4s = w4 * s, W5s = w5 * s, W6s = w6 * s, W7s = w7 * s, W8s = w8 * s;
    const float z0 = fmaxf(tb, 0.0f);                        // relu(BN(0)) for padded rows

    const int gw     = blockIdx.x * WPB + wid;               // global wave id
    const int stride = NBLK * WPB;
    const int niter  = (NPIL + stride - 1) / stride;         // uniform across grid

    for (int k = 0; k < niter; ++k) {
        const int  n      = gw + k * stride;
        const bool active = (n < NPIL);

        float2 v = make_float2(0.0f, 0.0f);
        int nv = 1, c2 = 0, c3 = 0;
        if (active) {
            // coalesced: lane i loads flat floats [2i, 2i+1] of this pillar's 128 floats
            v  = *reinterpret_cast<const float2*>(features + (size_t)n * (PPTS * 4) + 2 * lane);
            nv = num_voxels[n];
            c2 = coors[n * 4 + 2];
            c3 = coors[n * 4 + 3];
        }

        // stage pillar features into wave-private LDS for broadcast reads
        *reinterpret_cast<float2*>(&lds[wid][2 * lane]) = v;
        __syncthreads();   // uniform control flow; also forces LDS write drain

        // ---- mean over ALL 32 points (reference sums padding garbage too), ch 0..2 ----
        // even lanes hold (ch0, ch1), odd lanes hold (ch2, ch3); parity-preserving butterfly
        float sx = v.x, sy = v.y;
        #pragma unroll
        for (int msk = 2; msk <= 32; msk <<= 1) {
            sx += __shfl_xor(sx, msk, 64);
            sy += __shfl_xor(sy, msk, 64);
        }
        const float S0 = __shfl(sx, 0, 64);   // sum of channel 0
        const float S1 = __shfl(sy, 0, 64);   // sum of channel 1
        const float S2 = __shfl(sx, 1, 64);   // sum of channel 2
        const float inv = 1.0f / (float)nv;
        const float mx = S0 * inv, my = S1 * inv, mz = S2 * inv;
        const float cx = (float)c3 * 0.2f + 0.1f;
        const float cy = (float)c2 * 0.2f + (0.1f - 40.0f);

        // per-pillar constant term (mean/center offsets + BN bias), folded once per lane
        float B = tb;
        B = fmaf(-mx, W4s, B);
        B = fmaf(-my, W5s, B);
        B = fmaf(-mz, W6s, B);
        B = fmaf(-cx, W7s, B);
        B = fmaf(-cy, W8s, B);

        // max over valid points; padded rows contribute relu(tb) iff nv < 32
        float m = (nv < PPTS) ? z0 : 0.0f;
        const float4* lp = reinterpret_cast<const float4*>(lds[wid]);
        for (int p = 0; p < nv; ++p) {        // nv is wave-uniform -> uniform branch
            const float4 q = lp[p];           // uniform-address LDS broadcast
            const float y = fmaf(q.x, A0, fmaf(q.y, A1, fmaf(q.z, A2, fmaf(q.w, A3, B))));
            m = fmaxf(m, y);                  // relu folded into max (m >= 0 invariant)
        }

        if (active) out[(size_t)n * NUNITS + lane] = m;
        __syncthreads();   // uniform; orders next iteration's LDS overwrite
    }
}

extern "C" void kernel_launch(void* const* d_in, const int* in_sizes, int n_in,
                              void* d_out, int out_size, void* d_ws, size_t ws_size,
                              hipStream_t stream) {
    const float* features   = (const float*)d_in[0];
    const int*   num_voxels = (const int*)  d_in[1];
    const int*   coors      = (const int*)  d_in[2];
    const float* Wm         = (const float*)d_in[3];
    const float* gamma      = (const float*)d_in[4];
    const float* beta       = (const float*)d_in[5];
    const float* rmean      = (const float*)d_in[6];
    const float* rvar       = (const float*)d_in[7];
    float*       out        = (float*)d_out;

    hipLaunchKernelGGL(pfn_fused_kernel, dim3(NBLK), dim3(BLOCK), 0, stream,
                       features, num_voxels, coors, Wm, gamma, beta, rmean, rvar, out);
}

// Round 2
// 21.857 us; speedup vs baseline: 1.4230x; 1.4230x over previous
//
#include <hip/hip_runtime.h>
#include <math.h>

// PillarFeatureNet fused: decorate(9) -> linear(64) -> BN(eval) -> relu -> max over points.
// 1 wave = 1 pillar, lane = output unit. No block barriers (LDS is wave-private).
// Key algebra: y_p = dot(q_p, A) + B with B per-(pillar,unit) constant, and
// max_p(d_p + B) = max_p(d_p) + B  ->  the mean/center shuffle chain overlaps the point loop.

#define NPIL   40000
#define PPTS   32
#define NUNITS 64
#define NBLK   2048
#define WPB    4
#define BLOCK  (WPB * 64)

__global__ __launch_bounds__(BLOCK, 8)
void pfn_fused_kernel(const float* __restrict__ features,   // [N,32,4]
                      const int*   __restrict__ num_voxels, // [N]
                      const int*   __restrict__ coors,      // [N,4]
                      const float* __restrict__ Wm,         // [64,9]
                      const float* __restrict__ gamma,      // [64]
                      const float* __restrict__ beta,       // [64]
                      const float* __restrict__ rmean,      // [64]
                      const float* __restrict__ rvar,       // [64]
                      float* __restrict__ out)              // [N,64]
{
    __shared__ float lds[WPB][PPTS * 4];

    const int lane = threadIdx.x & 63;
    const int wid  = threadIdx.x >> 6;

    // per-lane (= per output unit) constants, amortized over the grid-stride loop
    const float w0 = Wm[lane * 9 + 0], w1 = Wm[lane * 9 + 1], w2 = Wm[lane * 9 + 2];
    const float w3 = Wm[lane * 9 + 3], w4 = Wm[lane * 9 + 4], w5 = Wm[lane * 9 + 5];
    const float w6 = Wm[lane * 9 + 6], w7 = Wm[lane * 9 + 7], w8 = Wm[lane * 9 + 8];
    const float s  = gamma[lane] * rsqrtf(rvar[lane] + 1e-3f);
    const float tb = beta[lane] - rmean[lane] * s;           // BN(0) = tb
    const float A0 = (w0 + w4 + w7) * s;
    const float A1 = (w1 + w5 + w8) * s;
    const float A2 = (w2 + w6) * s;
    const float A3 = w3 * s;
    const float W4s = w4 * s, W5s = w5 * s, W6s = w6 * s, W7s = w7 * s, W8s = w8 * s;

    const int gw     = blockIdx.x * WPB + wid;   // global wave id
    const int stride = NBLK * WPB;
    const int niter  = (NPIL + stride - 1) / stride;

    for (int k = 0; k < niter; ++k) {
        const int n = gw + k * stride;
        if (n >= NPIL) break;                       // wave-uniform
        const int nu = __builtin_amdgcn_readfirstlane(n);

        // coalesced: lane i loads flat floats [2i, 2i+1] of this pillar's 128 floats
        const float2 v = *reinterpret_cast<const float2*>(
            features + (size_t)nu * (PPTS * 4) + 2 * lane);
        const int nv = num_voxels[nu];              // scalar (s_load)
        const int c2 = coors[nu * 4 + 2];
        const int c3 = coors[nu * 4 + 3];
        int nvv = nv;                               // pin a VGPR copy for per-point cndmask
        asm volatile("" : "+v"(nvv));

        // stage pillar into wave-private LDS; wave-internal ordering only
        *reinterpret_cast<float2*>(&lds[wid][2 * lane]) = v;
        asm volatile("s_waitcnt lgkmcnt(0)" ::: "memory");
        __builtin_amdgcn_sched_barrier(0);

        // ---- max over points of the B-free dot (unrolled by 8 -> LDS reads pipeline) ----
        const int nvr = (nv + 7) & ~7;              // scalar loop bound (uniform branch)
        float m = -INFINITY;
        const float4* lp = reinterpret_cast<const float4*>(lds[wid]);
        for (int p0 = 0; p0 < nvr; p0 += 8) {
            #pragma unroll
            for (int j = 0; j < 8; ++j) {
                const int p = p0 + j;
                const float4 q = lp[p];             // uniform-address LDS broadcast
                float d = fmaf(q.x, A0, fmaf(q.y, A1, fmaf(q.z, A2, q.w * A3)));
                d = (p < nvv) ? d : -INFINITY;      // v_cmp(inline p) + v_cndmask
                m = fmaxf(m, d);
            }
        }

        // ---- mean over ALL 32 points (reference divides full sum by nv), ch 0..2 ----
        // even lanes hold (ch0,ch1), odd lanes (ch2,ch3); parity-preserving butterfly.
        // Needed only for B, i.e. only after the loop -> overlaps with it.
        float sx = v.x, sy = v.y;
        #pragma unroll
        for (int msk = 2; msk <= 32; msk <<= 1) {
            sx += __shfl_xor(sx, msk, 64);
            sy += __shfl_xor(sy, msk, 64);
        }
        const float S0 = __shfl(sx, 0, 64);
        const float S1 = __shfl(sy, 0, 64);
        const float S2 = __shfl(sx, 1, 64);
        const float inv = 1.0f / (float)nv;
        const float cx = (float)c3 * 0.2f + 0.1f;
        const float cy = (float)c2 * 0.2f + (0.1f - 40.0f);
        float B = tb;
        B = fmaf(-(S0 * inv), W4s, B);
        B = fmaf(-(S1 * inv), W5s, B);
        B = fmaf(-(S2 * inv), W6s, B);
        B = fmaf(-cx, W7s, B);
        B = fmaf(-cy, W8s, B);

        // result = max(0, max_valid(d)+B, padded? tb)
        float r = fmaxf(m + B, 0.0f);
        if (nv < PPTS) r = fmaxf(r, tb);

        out[(size_t)nu * NUNITS + lane] = r;
    }
}

extern "C" void kernel_launch(void* const* d_in, const int* in_sizes, int n_in,
                              void* d_out, int out_size, void* d_ws, size_t ws_size,
                              hipStream_t stream) {
    const float* features   = (const float*)d_in[0];
    const int*   num_voxels = (const int*)  d_in[1];
    const int*   coors      = (const int*)  d_in[2];
    const float* Wm         = (const float*)d_in[3];
    const float* gamma      = (const float*)d_in[4];
    const float* beta       = (const float*)d_in[5];
    const float* rmean      = (const float*)d_in[6];
    const float* rvar       = (const float*)d_in[7];
    float*       out        = (float*)d_out;

    hipLaunchKernelGGL(pfn_fused_kernel, dim3(NBLK), dim3(BLOCK), 0, stream,
                       features, num_voxels, coors, Wm, gamma, beta, rmean, rvar, out);
}

// Round 3
// 18.140 us; speedup vs baseline: 1.7146x; 1.2049x over previous
//
#include <hip/hip_runtime.h>
#include <math.h>

// PillarFeatureNet fused via MFMA: per pillar [32 pts x 4ch] * [4ch x 64 units],
// padding masked INSIDE the MFMA via a 5th K-slot flag * (-1e30) on the B side.
// Lane = point for loads/mean (no LDS staging); lane = unit for the output.
// B-term (mean/center/BN folds, incl. large ~80 center offsets) stays fp32 and
// hoists out of the max:  max_p(d_p + B) = max_p(d_p) + B.

#define NPIL   40000
#define PPTS   32
#define NUNITS 64
#define WPB    4
#define BLOCK  (WPB * 64)
#define NBLK   1024            // 4096 waves resident at 4 waves/SIMD; niter = 10

typedef float f32x16 __attribute__((ext_vector_type(16)));
typedef short bf16x8 __attribute__((ext_vector_type(8)));

// exact RNE f32 -> bf16 bit pattern (no API dependency)
__device__ __forceinline__ unsigned short f2bf(float f) {
    unsigned int u = __float_as_uint(f);
    u = u + 0x7FFFu + ((u >> 16) & 1u);
    return (unsigned short)(u >> 16);
}

template<int CTRL>
__device__ __forceinline__ float dpp_mov_f(float x) {
    return __int_as_float(__builtin_amdgcn_update_dpp(
        0, __float_as_int(x), CTRL, 0xF, 0xF, true));
}

// sum over lanes 0..31 (VALU/DPP only), broadcast via readlane(31)
__device__ __forceinline__ float lo32_sum(float x) {
    x += dpp_mov_f<0x111>(x);   // row_shr:1
    x += dpp_mov_f<0x112>(x);   // row_shr:2
    x += dpp_mov_f<0x114>(x);   // row_shr:4
    x += dpp_mov_f<0x118>(x);   // row_shr:8  -> lane15/31 hold row sums
    x += dpp_mov_f<0x142>(x);   // row_bcast:15 -> lane31 = sum(lanes 0..31)
    return __int_as_float(__builtin_amdgcn_readlane(__float_as_int(x), 31));
}

__device__ __forceinline__ float max16(const f32x16& a) {
    float x0 = fmaxf(a[0], a[1]),   x1 = fmaxf(a[2], a[3]);
    float x2 = fmaxf(a[4], a[5]),   x3 = fmaxf(a[6], a[7]);
    float x4 = fmaxf(a[8], a[9]),   x5 = fmaxf(a[10], a[11]);
    float x6 = fmaxf(a[12], a[13]), x7 = fmaxf(a[14], a[15]);
    float y0 = fmaxf(x0, x1), y1 = fmaxf(x2, x3);
    float y2 = fmaxf(x4, x5), y3 = fmaxf(x6, x7);
    return fmaxf(fmaxf(y0, y1), fmaxf(y2, y3));
}

__global__ __launch_bounds__(BLOCK, 4)
void pfn_mfma_kernel(const float* __restrict__ features,   // [N,32,4]
                     const int*   __restrict__ num_voxels, // [N]
                     const int*   __restrict__ coors,      // [N,4]
                     const float* __restrict__ Wm,         // [64,9]
                     const float* __restrict__ gamma,
                     const float* __restrict__ beta,
                     const float* __restrict__ rmean,
                     const float* __restrict__ rvar,
                     float* __restrict__ out)               // [N,64]
{
    const int  lane   = threadIdx.x & 63;
    const int  wid    = threadIdx.x >> 6;
    const int  lo31   = lane & 31;
    const bool lohalf = (lane < 32);

    // ---- hoisted: fp32 B-fold coefficients for unit = lane ----
    const float s_l = gamma[lane] * rsqrtf(rvar[lane] + 1e-3f);
    const float tb  = beta[lane] - rmean[lane] * s_l;
    const float W4s = Wm[lane*9+4]*s_l, W5s = Wm[lane*9+5]*s_l, W6s = Wm[lane*9+6]*s_l;
    const float W7s = Wm[lane*9+7]*s_l, W8s = Wm[lane*9+8]*s_l;

    // ---- hoisted: B-operand weight fragments (units 0..31 -> bf0, 32..63 -> bf1) ----
    // layout: low lanes carry k=0..7 chunk (k0-3 = folded coeffs, k4 = -1e30 mask row),
    // high lanes carry k=8..15 (all zero). Only A/B k-map SYMMETRY is assumed.
    bf16x8 bf0 = {0,0,0,0,0,0,0,0}, bf1 = {0,0,0,0,0,0,0,0};
    if (lohalf) {
        const int u0 = lo31, u1 = lo31 + 32;
        const float s0 = gamma[u0] * rsqrtf(rvar[u0] + 1e-3f);
        const float s1 = gamma[u1] * rsqrtf(rvar[u1] + 1e-3f);
        const float* w0 = Wm + u0*9;
        const float* w1 = Wm + u1*9;
        bf0[0] = (short)f2bf((w0[0]+w0[4]+w0[7])*s0);
        bf0[1] = (short)f2bf((w0[1]+w0[5]+w0[8])*s0);
        bf0[2] = (short)f2bf((w0[2]+w0[6])*s0);
        bf0[3] = (short)f2bf(w0[3]*s0);
        bf0[4] = (short)f2bf(-1e30f);
        bf1[0] = (short)f2bf((w1[0]+w1[4]+w1[7])*s1);
        bf1[1] = (short)f2bf((w1[1]+w1[5]+w1[8])*s1);
        bf1[2] = (short)f2bf((w1[2]+w1[6])*s1);
        bf1[3] = (short)f2bf(w1[3]*s1);
        bf1[4] = (short)f2bf(-1e30f);
    }

    const float qm    = lohalf ? 1.0f : 0.0f;   // zero A-features in high lanes
    const int   plane = lohalf ? lo31 : -1;     // -1 => mask flag never set in high lanes

    const int stride = NBLK * WPB;
    const int niter  = (NPIL + stride - 1) / stride;
    int n = blockIdx.x * WPB + wid;

    // prologue loads (clamped)
    int nu  = __builtin_amdgcn_readfirstlane(n);
    int ncl = (nu < NPIL) ? nu : (NPIL - 1);
    float4 q = *reinterpret_cast<const float4*>(features + (size_t)ncl*128 + lo31*4);
    int nv = num_voxels[ncl];
    int c2 = coors[ncl*4+2], c3 = coors[ncl*4+3];

    for (int k = 0; k < niter; ++k) {
        // ---- prefetch next pillar (clamped; covers ~full iteration of compute) ----
        const int nn   = n + stride;
        const int nun  = __builtin_amdgcn_readfirstlane(nn);
        const int ncln = (nun < NPIL) ? nun : (NPIL - 1);
        const float4 qn = *reinterpret_cast<const float4*>(features + (size_t)ncln*128 + lo31*4);
        const int nvn = num_voxels[ncln];
        const int c2n = coors[ncln*4+2], c3n = coors[ncln*4+3];

        // ---- A fragment: lane = point lo31, k0-3 = bf16 features, k4 = pad flag ----
        bf16x8 af;
        af[0] = (short)f2bf(q.x * qm);
        af[1] = (short)f2bf(q.y * qm);
        af[2] = (short)f2bf(q.z * qm);
        af[3] = (short)f2bf(q.w * qm);
        af[4] = (plane >= nv) ? (short)0x3F80 : (short)0;   // 1.0bf16 on invalid rows
        af[5] = 0; af[6] = 0; af[7] = 0;

        f32x16 z;
        #pragma unroll
        for (int i = 0; i < 16; ++i) z[i] = 0.0f;
        const f32x16 acc0 = __builtin_amdgcn_mfma_f32_32x32x16_bf16(af, bf0, z, 0, 0, 0);
        const f32x16 acc1 = __builtin_amdgcn_mfma_f32_32x32x16_bf16(af, bf1, z, 0, 0, 0);

        // ---- pillar mean over ALL 32 raw points (fp32, DPP-only) ----
        const float S0 = lo32_sum(q.x);
        const float S1 = lo32_sum(q.y);
        const float S2 = lo32_sum(q.z);
        const float inv = 1.0f / (float)nv;
        const float cx = (float)c3 * 0.2f + 0.1f;
        const float cy = (float)c2 * 0.2f + (0.1f - 40.0f);
        float B = tb;
        B = fmaf(-(S0 * inv), W4s, B);
        B = fmaf(-(S1 * inv), W5s, B);
        B = fmaf(-(S2 * inv), W6s, B);
        B = fmaf(-cx, W7s, B);
        B = fmaf(-cy, W8s, B);

        // ---- epilogue: max over all 32 rows (invalid rows are ~-1e30) ----
        float m0 = max16(acc0);
        float m1 = max16(acc1);
        m0 = fmaxf(m0, __shfl_xor(m0, 32, 64));   // rows split across lane^32
        m1 = fmaxf(m1, __shfl_xor(m1, 32, 64));
        const float mine = lohalf ? m0 : m1;      // unit = lane
        float r = fmaxf(mine + B, 0.0f);
        r = fmaxf(r, (nv < PPTS) ? tb : -INFINITY);  // padded rows contribute relu(tb)

        if (n < NPIL) out[(size_t)nu * NUNITS + lane] = r;

        // rotate prefetched state
        n = nn; nu = nun; q = qn; nv = nvn; c2 = c2n; c3 = c3n;
    }
}

extern "C" void kernel_launch(void* const* d_in, const int* in_sizes, int n_in,
                              void* d_out, int out_size, void* d_ws, size_t ws_size,
                              hipStream_t stream) {
    const float* features   = (const float*)d_in[0];
    const int*   num_voxels = (const int*)  d_in[1];
    const int*   coors      = (const int*)  d_in[2];
    const float* Wm         = (const float*)d_in[3];
    const float* gamma      = (const float*)d_in[4];
    const float* beta       = (const float*)d_in[5];
    const float* rmean      = (const float*)d_in[6];
    const float* rvar       = (const float*)d_in[7];
    float*       out        = (float*)d_out;

    hipLaunchKernelGGL(pfn_mfma_kernel, dim3(NBLK), dim3(BLOCK), 0, stream,
                       features, num_voxels, coors, Wm, gamma, beta, rmean, rvar, out);
}

// Round 4
// 17.068 us; speedup vs baseline: 1.8222x; 1.0628x over previous
//
#include <hip/hip_runtime.h>
#include <hip/hip_bf16.h>
#include <math.h>

// PillarFeatureNet fully inside MFMA k-space.
// Per pillar: D[32 pts x 64 units] = A[32 x 16] * B[16 x 64], two 32x32x16 bf16 MFMAs.
// k 0-3 : raw features (f0..f3)        x (W0+W4+W7, W1+W5+W8, W2+W6, W3)*s
// k 4-6 : -mean (per-row, masked)      x (W4,W5,W6)*s
// k 7   : unused
// k 8-11: -cx_hi,-cx_lo,-cy_hi,-cy_lo  x (W7s,W7s,W8s,W8s)   (exact f32 split)
// k12-13: 1.0 (never masked)           x (tb_hi, tb_lo)      -> invalid rows = tb exactly
// Padded rows: zero k0-6/k8-11 via cndmask -> acc = tb -> reference's relu(tb) via final max(.,0).
// Wave owns 8 CONTIGUOUS pillars: all feature loads + one batched nv/coors load
// issued at wave start (8-deep prefetch, no per-iteration scalar loads).

#define NPIL  40000
#define NITER 8
#define WPB   4
#define BLOCK (WPB * 64)
#define NBLK  (NPIL / (WPB * NITER))   // 1250

typedef float f32x16 __attribute__((ext_vector_type(16)));
typedef short bf16x8 __attribute__((ext_vector_type(8)));

union frag_u { bf16x8 h; int4 w; };

// pack (bf16(a), bf16(b)) into one dword (compiler fuses to v_cvt_pk_bf16_f32)
__device__ __forceinline__ int pk(float a, float b) {
    unsigned lo = (unsigned)__bfloat16_as_ushort(__float2bfloat16(a));
    unsigned hi = (unsigned)__bfloat16_as_ushort(__float2bfloat16(b));
    return (int)(lo | (hi << 16));
}
__device__ __forceinline__ float bfround(float x) {   // f32 value of bf16(x)
    return __bfloat162float(__float2bfloat16(x));
}

template<int CTRL>
__device__ __forceinline__ float dpp_add(float x) {
    return x + __int_as_float(__builtin_amdgcn_update_dpp(
        0, __float_as_int(x), CTRL, 0xF, 0xF, true));
}
// sum over lanes 0..31, broadcast to all lanes (lanes 32..63 hold copies of 0..31)
__device__ __forceinline__ float lo32_sum(float x) {
    x = dpp_add<0x111>(x);   // row_shr:1
    x = dpp_add<0x112>(x);   // row_shr:2
    x = dpp_add<0x114>(x);   // row_shr:4
    x = dpp_add<0x118>(x);   // row_shr:8
    x = dpp_add<0x142>(x);   // row_bcast:15 -> lane31 = sum(0..31)
    return __int_as_float(__builtin_amdgcn_readlane(__float_as_int(x), 31));
}

__device__ __forceinline__ float vmax16(const f32x16& a) {   // max3-fusable tree
    float t0 = fmaxf(fmaxf(a[0],  a[1]),  a[2]);
    float t1 = fmaxf(fmaxf(a[3],  a[4]),  a[5]);
    float t2 = fmaxf(fmaxf(a[6],  a[7]),  a[8]);
    float t3 = fmaxf(fmaxf(a[9],  a[10]), a[11]);
    float t4 = fmaxf(fmaxf(a[12], a[13]), a[14]);
    float u0 = fmaxf(fmaxf(t0, t1), t2);
    float u1 = fmaxf(fmaxf(t3, t4), a[15]);
    return fmaxf(u0, u1);
}

__global__ __launch_bounds__(BLOCK, 4)
void pfn_mfma_kernel(const float* __restrict__ features,   // [N,32,4]
                     const int*   __restrict__ num_voxels, // [N]
                     const int*   __restrict__ coors,      // [N,4]
                     const float* __restrict__ Wm,         // [64,9]
                     const float* __restrict__ gamma,
                     const float* __restrict__ beta,
                     const float* __restrict__ rmean,
                     const float* __restrict__ rvar,
                     float* __restrict__ out)               // [N,64]
{
    const int  lane = threadIdx.x & 63;
    const int  wid  = threadIdx.x >> 6;
    const int  lo31 = lane & 31;
    const bool hih  = (lane >= 32);

    const int p0 = (blockIdx.x * WPB + wid) * NITER;   // 8 contiguous pillars

    // ---- issue ALL memory up front: 8 feature tiles + batched nv/coors ----
    const float* fbase = features + (size_t)p0 * 128 + lo31 * 4;
    float4 qv[NITER];
    #pragma unroll
    for (int j = 0; j < NITER; ++j)
        qv[j] = *reinterpret_cast<const float4*>(fbase + (size_t)j * 128);
    const int  li   = (lane < NITER) ? lane : (NITER - 1);
    const int  nv8  = num_voxels[p0 + li];                                  // lane j -> nv of pillar j
    const int2 cc8  = *reinterpret_cast<const int2*>(coors + (p0 + li) * 4 + 2); // (c2,c3), 8B-aligned

    // ---- per-lane B-fragments (col = lane&31 = unit; built once, used 8x) ----
    frag_u bf0, bf1;
    {
        const int u = lo31;
        #pragma unroll
        for (int t = 0; t < 2; ++t) {
            const int uu = u + t * 32;
            const float* w = Wm + uu * 9;
            const float s  = gamma[uu] * rsqrtf(rvar[uu] + 1e-3f);
            const float tb = beta[uu] - rmean[uu] * s;
            int4 r;
            if (!hih) {                       // k0-7 chunk
                r.x = pk((w[0] + w[4] + w[7]) * s, (w[1] + w[5] + w[8]) * s);
                r.y = pk((w[2] + w[6]) * s,        w[3] * s);
                r.z = pk(w[4] * s,                 w[5] * s);
                r.w = pk(w[6] * s,                 0.0f);
            } else {                          // k8-15 chunk
                const float w7s = w[7] * s, w8s = w[8] * s;
                r.x = pk(w7s, w7s);
                r.y = pk(w8s, w8s);
                r.z = pk(tb,  tb - bfround(tb));   // (tb_hi, tb_lo)
                r.w = 0;
            }
            if (t == 0) bf0.w = r; else bf1.w = r;
        }
    }

    f32x16 z;
    #pragma unroll
    for (int i = 0; i < 16; ++i) z[i] = 0.0f;

    const int ONE2 = 0x3F803F80;                 // pack(1.0bf, 1.0bf)
    const int inv2 = hih ? ONE2 : 0;             // invalid-row value of word2

    #pragma unroll
    for (int j = 0; j < NITER; ++j) {
        const int   snv = __builtin_amdgcn_readlane(nv8,   j);
        const int   sc2 = __builtin_amdgcn_readlane(cc8.x, j);
        const int   sc3 = __builtin_amdgcn_readlane(cc8.y, j);
        const float4 q  = qv[j];

        // pillar mean over all 32 rows (reference semantics: full sum / nv)
        const float S0 = lo32_sum(q.x);
        const float S1 = lo32_sum(q.y);
        const float S2 = lo32_sum(q.z);
        const float rn = __builtin_amdgcn_rcpf((float)snv);   // |err| ~1e-7 << bf16 lsb
        const float cx = (float)sc3 * 0.2f + 0.1f;
        const float cy = (float)sc2 * 0.2f + (0.1f - 40.0f);

        // A-fragment words (4 dwords = 8 bf16 k-slots per lane)
        const int f01 = pk(q.x, q.y);
        const int f23 = pk(q.z, q.w);
        const int mxy = pk(-S0 * rn, -S1 * rn);
        const int mz0 = pk(-S2 * rn, 0.0f);
        const int cxw = pk(-cx, -cx - bfround(-cx));          // exact split
        const int cyw = pk(-cy, -cy - bfround(-cy));

        const bool valid = (lo31 < snv);
        int w0 = hih ? cxw  : f01;  w0 = valid ? w0 : 0;
        int w1 = hih ? cyw  : f23;  w1 = valid ? w1 : 0;
        int w2 = hih ? ONE2 : mxy;  w2 = valid ? w2 : inv2;   // k12/13 (=1.0) never masked
        int w3 = hih ? 0    : mz0;  w3 = valid ? w3 : 0;
        frag_u af; af.w = make_int4(w0, w1, w2, w3);

        const f32x16 a0 = __builtin_amdgcn_mfma_f32_32x32x16_bf16(af.h, bf0.h, z, 0, 0, 0);
        const f32x16 a1 = __builtin_amdgcn_mfma_f32_32x32x16_bf16(af.h, bf1.h, z, 0, 0, 0);

        // max over 32 rows: per-lane 16, then lane^32 exchange (one shuffle: send
        // what the partner needs), unit = lane
        const float m0 = vmax16(a0);
        const float m1 = vmax16(a1);
        const float got  = __shfl_xor(hih ? m0 : m1, 32, 64);
        const float mine = hih ? m1 : m0;
        const float r = fmaxf(fmaxf(mine, got), 0.0f);   // relu: max_p relu(y) = max(0, max_p y)

        out[(size_t)(p0 + j) * 64 + lane] = r;
    }
}

extern "C" void kernel_launch(void* const* d_in, const int* in_sizes, int n_in,
                              void* d_out, int out_size, void* d_ws, size_t ws_size,
                              hipStream_t stream) {
    const float* features   = (const float*)d_in[0];
    const int*   num_voxels = (const int*)  d_in[1];
    const int*   coors      = (const int*)  d_in[2];
    const float* Wm         = (const float*)d_in[3];
    const float* gamma      = (const float*)d_in[4];
    const float* beta       = (const float*)d_in[5];
    const float* rmean      = (const float*)d_in[6];
    const float* rvar       = (const float*)d_in[7];
    float*       out        = (float*)d_out;

    hipLaunchKernelGGL(pfn_mfma_kernel, dim3(NBLK), dim3(BLOCK), 0, stream,
                       features, num_voxels, coors, Wm, gamma, beta, rmean, rvar, out);
}